// Round 2
// baseline (25406.671 us; speedup 1.0000x reference)
//
#include <hip/hip_runtime.h>
#include <hip/hip_bf16.h>
#include <math.h>

#define B 64
#define S 512
#define H 512

__device__ __forceinline__ float sigmoidf_(float x) {
    return 1.0f / (1.0f + __expf(-x));
}

// One LSTM timestep. Grid: 256 blocks x 128 threads.
// Block bid owns hidden columns k = {2*bid, 2*bid+1}.
// Thread tid: b = tid & 63, k = 2*bid + (tid >> 6).
// Each thread computes all 4 gate dot products for its (b, k), then the
// elementwise update -> no cross-thread combine needed within a step.
// h is double-buffered across steps (read h_prev, write h_next); c is
// owner-private (same thread reads/writes c[b*H+k]) so single-buffered.
// All float tensors are fp32 (reference dtype). Weight-row loads are
// wave-uniform (k fixed per wave) -> broadcast from cache.
__global__ __launch_bounds__(128)
void lstm_step(const int* __restrict__ tokens,
               const float* __restrict__ emb,
               const float* __restrict__ W_ih,
               const float* __restrict__ W_hh,
               const float* __restrict__ b_ih,
               const float* __restrict__ b_hh,
               const float* __restrict__ h_prev,
               float* __restrict__ h_next,
               float* __restrict__ c_st,
               float* __restrict__ out,
               int t)
{
    const int tid = threadIdx.x;
    const int b   = tid & 63;
    const int k   = blockIdx.x * 2 + (tid >> 6);   // 0..511

    const int token = tokens[b * S + t];
    const float* xrow = emb + (size_t)token * H;
    const float* hrow = h_prev + b * H;

    // bias = b_ih + b_hh; gate order i,f,g,o at offsets 0,512,1024,1536
    float acc0 = b_ih[k]        + b_hh[k];
    float acc1 = b_ih[512 + k]  + b_hh[512 + k];
    float acc2 = b_ih[1024 + k] + b_hh[1024 + k];
    float acc3 = b_ih[1536 + k] + b_hh[1536 + k];

    const float4* x4  = reinterpret_cast<const float4*>(xrow);
    const float4* h4  = reinterpret_cast<const float4*>(hrow);
    const float4* wi0 = reinterpret_cast<const float4*>(W_ih + (size_t)(k)        * H);
    const float4* wi1 = reinterpret_cast<const float4*>(W_ih + (size_t)(512 + k)  * H);
    const float4* wi2 = reinterpret_cast<const float4*>(W_ih + (size_t)(1024 + k) * H);
    const float4* wi3 = reinterpret_cast<const float4*>(W_ih + (size_t)(1536 + k) * H);
    const float4* wh0 = reinterpret_cast<const float4*>(W_hh + (size_t)(k)        * H);
    const float4* wh1 = reinterpret_cast<const float4*>(W_hh + (size_t)(512 + k)  * H);
    const float4* wh2 = reinterpret_cast<const float4*>(W_hh + (size_t)(1024 + k) * H);
    const float4* wh3 = reinterpret_cast<const float4*>(W_hh + (size_t)(1536 + k) * H);

    #pragma unroll 2
    for (int q = 0; q < H / 4; ++q) {
        const float4 xv = x4[q];
        const float4 hv = h4[q];

        float4 w;
        w = wi0[q];
        acc0 += xv.x*w.x + xv.y*w.y + xv.z*w.z + xv.w*w.w;
        w = wi1[q];
        acc1 += xv.x*w.x + xv.y*w.y + xv.z*w.z + xv.w*w.w;
        w = wi2[q];
        acc2 += xv.x*w.x + xv.y*w.y + xv.z*w.z + xv.w*w.w;
        w = wi3[q];
        acc3 += xv.x*w.x + xv.y*w.y + xv.z*w.z + xv.w*w.w;

        w = wh0[q];
        acc0 += hv.x*w.x + hv.y*w.y + hv.z*w.z + hv.w*w.w;
        w = wh1[q];
        acc1 += hv.x*w.x + hv.y*w.y + hv.z*w.z + hv.w*w.w;
        w = wh2[q];
        acc2 += hv.x*w.x + hv.y*w.y + hv.z*w.z + hv.w*w.w;
        w = wh3[q];
        acc3 += hv.x*w.x + hv.y*w.y + hv.z*w.z + hv.w*w.w;
    }

    const float ig = sigmoidf_(acc0);
    const float fg = sigmoidf_(acc1);
    const float gg = tanhf(acc2);
    const float og = sigmoidf_(acc3);

    const int ck = b * H + k;
    const float cn = fg * c_st[ck] + ig * gg;
    c_st[ck] = cn;
    const float hn = og * tanhf(cn);
    h_next[ck] = hn;

    // annotations: out[b*S*H + t*H + k]
    out[(size_t)b * S * H + (size_t)t * H + k] = hn;
    if (t == S - 1) {
        out[(size_t)B * S * H + ck]         = hn;  // final h
        out[(size_t)B * S * H + B * H + ck] = cn;  // final c
    }
}

extern "C" void kernel_launch(void* const* d_in, const int* in_sizes, int n_in,
                              void* d_out, int out_size, void* d_ws, size_t ws_size,
                              hipStream_t stream)
{
    const int*   tokens = (const int*)d_in[0];
    const float* emb    = (const float*)d_in[1];
    const float* W_ih   = (const float*)d_in[2];
    const float* W_hh   = (const float*)d_in[3];
    const float* b_ih   = (const float*)d_in[4];
    const float* b_hh   = (const float*)d_in[5];
    float* out = (float*)d_out;

    // ws layout: c[B*H] f32 | h0[B*H] f32 | h1[B*H] f32
    float* c_st = (float*)d_ws;
    float* h0   = c_st + B * H;
    float* h1   = h0 + B * H;
    hipMemsetAsync(d_ws, 0, (size_t)3 * B * H * sizeof(float), stream);

    for (int t = 0; t < S; ++t) {
        const float* hp = (t & 1) ? h1 : h0;
        float*       hn = (t & 1) ? h0 : h1;
        lstm_step<<<dim3(256), dim3(128), 0, stream>>>(
            tokens, emb, W_ih, W_hh, b_ih, b_hh, hp, hn, c_st, out, t);
    }
}

// Round 4
// 8658.651 us; speedup vs baseline: 2.9343x; 2.9343x over previous
//
#include <hip/hip_runtime.h>
#include <math.h>

#define B 64
#define S 512
#define H 512
#define G4 2048  // 4*H gate columns

__device__ __forceinline__ float sigmoidf_(float x) {
    return 1.0f / (1.0f + __expf(-x));
}

// bf16 <-> f32 via raw bits (avoids __hip_bfloat16 API drift)
__device__ __forceinline__ ushort f2bf(float f) {
    union { float f; unsigned int u; } v; v.f = f;
    unsigned int r = v.u + 0x7FFFu + ((v.u >> 16) & 1u);  // round-nearest-even
    return (ushort)(r >> 16);
}
__device__ __forceinline__ float bf2f(ushort s) {
    union { unsigned int u; float f; } v; v.u = ((unsigned int)s) << 16;
    return v.f;
}

// ---------------------------------------------------------------------------
// Kernel 1: xg[t][g][b] = sum_d emb[tok[b][t]][d] * W_ih[g][d] + (b_ih+b_hh)[g]
// stored bf16. Grid (512 t, 16 gtiles of 128), 256 threads.
// Register blocking: each thread computes 4 b x 8 g outputs, K chunked by 64.
// ---------------------------------------------------------------------------
__global__ __launch_bounds__(256)
void xg_gemm(const int* __restrict__ tokens,
             const float* __restrict__ emb,
             const float* __restrict__ W_ih,
             const float* __restrict__ b_ih,
             const float* __restrict__ b_hh,
             ushort* __restrict__ xg)
{
    const int t      = blockIdx.x;
    const int g_base = blockIdx.y * 128;
    const int tid    = threadIdx.x;

    // staging roles
    const int b_ld = tid >> 2;          // 0..63
    const int seg  = tid & 3;           // 0..3  (16 d each)
    const int r_w  = tid >> 1;          // 0..127 weight row
    const int half = tid & 1;           // 0..1  (32 d each)
    // compute roles
    const int b0 = (tid & 15) * 4;      // 4 batches
    const int g0 = (tid >> 4) * 8;      // 8 gates

    const int token = tokens[b_ld * S + t];
    const float4* embrow = reinterpret_cast<const float4*>(emb) + (size_t)token * (H / 4);

    __shared__ float hs[64][64];     // [d_local][b]
    __shared__ float ws[128][68];    // [g_local][d_local] pad 68 (16B-aligned rows)

    float acc[4][8];
    #pragma unroll
    for (int i = 0; i < 4; ++i)
        #pragma unroll
        for (int j = 0; j < 8; ++j) acc[i][j] = 0.0f;

    for (int kc = 0; kc < 8; ++kc) {
        const int d0 = kc * 64;
        // stage A: 64 d x 64 b from gathered emb rows
        #pragma unroll
        for (int i = 0; i < 4; ++i) {
            const int dl = seg * 16 + i * 4;
            const float4 f = embrow[(d0 >> 2) + seg * 4 + i];
            hs[dl + 0][b_ld] = f.x;
            hs[dl + 1][b_ld] = f.y;
            hs[dl + 2][b_ld] = f.z;
            hs[dl + 3][b_ld] = f.w;
        }
        // stage W: 128 g x 64 d
        const float4* wrow = reinterpret_cast<const float4*>(W_ih) +
                             (size_t)(g_base + r_w) * (H / 4) + (d0 >> 2) + half * 8;
        #pragma unroll
        for (int i = 0; i < 8; ++i) {
            *reinterpret_cast<float4*>(&ws[r_w][half * 32 + i * 4]) = wrow[i];
        }
        __syncthreads();

        #pragma unroll
        for (int d4 = 0; d4 < 16; ++d4) {
            const float4 hv0 = *reinterpret_cast<const float4*>(&hs[d4 * 4 + 0][b0]);
            const float4 hv1 = *reinterpret_cast<const float4*>(&hs[d4 * 4 + 1][b0]);
            const float4 hv2 = *reinterpret_cast<const float4*>(&hs[d4 * 4 + 2][b0]);
            const float4 hv3 = *reinterpret_cast<const float4*>(&hs[d4 * 4 + 3][b0]);
            #pragma unroll
            for (int gg = 0; gg < 8; ++gg) {
                const float4 w = *reinterpret_cast<const float4*>(&ws[g0 + gg][d4 * 4]);
                acc[0][gg] += hv0.x * w.x + hv1.x * w.y + hv2.x * w.z + hv3.x * w.w;
                acc[1][gg] += hv0.y * w.x + hv1.y * w.y + hv2.y * w.z + hv3.y * w.w;
                acc[2][gg] += hv0.z * w.x + hv1.z * w.y + hv2.z * w.z + hv3.z * w.w;
                acc[3][gg] += hv0.w * w.x + hv1.w * w.y + hv2.w * w.z + hv3.w * w.w;
            }
        }
        __syncthreads();
    }

    // bias + bf16 store: xg[t][g][b], b contiguous
    #pragma unroll
    for (int gg = 0; gg < 8; ++gg) {
        const int g = g_base + g0 + gg;
        const float bias = b_ih[g] + b_hh[g];
        ushort4 us;
        us.x = f2bf(acc[0][gg] + bias);
        us.y = f2bf(acc[1][gg] + bias);
        us.z = f2bf(acc[2][gg] + bias);
        us.w = f2bf(acc[3][gg] + bias);
        *reinterpret_cast<ushort4*>(&xg[((size_t)t * G4 + g) * 64 + b0]) = us;
    }
}

// ---------------------------------------------------------------------------
// Kernel 2: one recurrent step. Grid 512 blocks (one hidden column k each),
// 256 threads = 64 b x 4 K-quarters. h kept transposed: hist[t][d][b].
// ---------------------------------------------------------------------------
__global__ __launch_bounds__(256)
void lstm_step(const float* __restrict__ W_hh,
               const ushort* __restrict__ xg,
               float* __restrict__ hist,   // [S+1][H][B]
               float* __restrict__ c_st,   // [H][B]
               int t)
{
    const int k   = blockIdx.x;
    const int tid = threadIdx.x;
    const int b   = tid & 63;
    const int sp  = tid >> 6;          // 0..3
    const int d0  = sp * 128;

    const float* hp = hist + (size_t)t * (H * B) + (size_t)d0 * B + b;

    const float4* w0 = reinterpret_cast<const float4*>(W_hh + ((size_t)(0 * H + k)) * H + d0);
    const float4* w1 = reinterpret_cast<const float4*>(W_hh + ((size_t)(1 * H + k)) * H + d0);
    const float4* w2 = reinterpret_cast<const float4*>(W_hh + ((size_t)(2 * H + k)) * H + d0);
    const float4* w3 = reinterpret_cast<const float4*>(W_hh + ((size_t)(3 * H + k)) * H + d0);

    float a0 = 0.f, a1 = 0.f, a2 = 0.f, a3 = 0.f;

    #pragma unroll 4
    for (int q = 0; q < 32; ++q) {
        const float h0 = hp[(q * 4 + 0) * B];
        const float h1 = hp[(q * 4 + 1) * B];
        const float h2 = hp[(q * 4 + 2) * B];
        const float h3 = hp[(q * 4 + 3) * B];
        float4 w;
        w = w0[q]; a0 += h0 * w.x + h1 * w.y + h2 * w.z + h3 * w.w;
        w = w1[q]; a1 += h0 * w.x + h1 * w.y + h2 * w.z + h3 * w.w;
        w = w2[q]; a2 += h0 * w.x + h1 * w.y + h2 * w.z + h3 * w.w;
        w = w3[q]; a3 += h0 * w.x + h1 * w.y + h2 * w.z + h3 * w.w;
    }

    __shared__ float part[16][64];
    part[0 * 4 + sp][b] = a0;
    part[1 * 4 + sp][b] = a1;
    part[2 * 4 + sp][b] = a2;
    part[3 * 4 + sp][b] = a3;
    __syncthreads();

    if (tid < 64) {
        float v[4];
        #pragma unroll
        for (int g = 0; g < 4; ++g) {
            float s = part[g * 4 + 0][tid] + part[g * 4 + 1][tid] +
                      part[g * 4 + 2][tid] + part[g * 4 + 3][tid];
            v[g] = s + bf2f(xg[((size_t)t * G4 + g * H + k) * 64 + tid]);
        }
        const float ig = sigmoidf_(v[0]);
        const float fg = sigmoidf_(v[1]);
        const float gg = tanhf(v[2]);
        const float og = sigmoidf_(v[3]);

        const int ck = k * B + tid;
        const float cn = fg * c_st[ck] + ig * gg;
        c_st[ck] = cn;
        hist[(size_t)(t + 1) * (H * B) + ck] = og * tanhf(cn);
    }
}

// ---------------------------------------------------------------------------
// Kernel 3: finalize. Transpose hist[1..512][k][b] -> out[b][t][k]; slot 512
// of grid.x also writes final h (hist[512]) and final c. Grid (513, 8), 256 thr.
// ---------------------------------------------------------------------------
__global__ __launch_bounds__(256)
void finalize(const float* __restrict__ hist,
              const float* __restrict__ c_st,
              float* __restrict__ out)
{
    const int ts  = blockIdx.x;       // 0..512
    const int k0  = blockIdx.y * 64;
    const int tid = threadIdx.x;

    __shared__ float tile[64][65];    // [k_local][b]

    const int b_ld = tid & 63;
    const int kr   = tid >> 6;        // 0..3

    const int kw   = (tid & 15) * 4;  // write-phase k offset (4 wide)
    const int brow = tid >> 4;        // 0..15

    if (ts < S) {
        const float* src = hist + (size_t)(ts + 1) * (H * B) + (size_t)k0 * B;
        #pragma unroll
        for (int i = 0; i < 16; ++i) {
            const int kk = kr * 16 + i;
            tile[kk][b_ld] = src[(size_t)kk * B + b_ld];
        }
        __syncthreads();
        #pragma unroll
        for (int i = 0; i < 4; ++i) {
            const int b = brow + 16 * i;
            float4 v;
            v.x = tile[kw + 0][b];
            v.y = tile[kw + 1][b];
            v.z = tile[kw + 2][b];
            v.w = tile[kw + 3][b];
            *reinterpret_cast<float4*>(&out[((size_t)b * S + ts) * H + k0 + kw]) = v;
        }
    } else {
        // final h from hist[S], final c from c_st
        const float* srcs[2] = { hist + (size_t)S * (H * B) + (size_t)k0 * B,
                                 c_st + (size_t)k0 * B };
        float* dsts[2] = { out + (size_t)B * S * H,
                           out + (size_t)B * S * H + (size_t)B * H };
        for (int which = 0; which < 2; ++which) {
            __syncthreads();
            #pragma unroll
            for (int i = 0; i < 16; ++i) {
                const int kk = kr * 16 + i;
                tile[kk][b_ld] = srcs[which][(size_t)kk * B + b_ld];
            }
            __syncthreads();
            #pragma unroll
            for (int i = 0; i < 4; ++i) {
                const int b = brow + 16 * i;
                float4 v;
                v.x = tile[kw + 0][b];
                v.y = tile[kw + 1][b];
                v.z = tile[kw + 2][b];
                v.w = tile[kw + 3][b];
                *reinterpret_cast<float4*>(&dsts[which][(size_t)b * H + k0 + kw]) = v;
            }
        }
    }
}

// ---------------------------------------------------------------------------
// Fallback (round-2 path) if ws_size is too small for the staged pipeline.
// ---------------------------------------------------------------------------
__global__ __launch_bounds__(128)
void lstm_step_fb(const int* __restrict__ tokens,
                  const float* __restrict__ emb,
                  const float* __restrict__ W_ih,
                  const float* __restrict__ W_hh,
                  const float* __restrict__ b_ih,
                  const float* __restrict__ b_hh,
                  const float* __restrict__ h_prev,
                  float* __restrict__ h_next,
                  float* __restrict__ c_st,
                  float* __restrict__ out,
                  int t)
{
    const int tid = threadIdx.x;
    const int b   = tid & 63;
    const int k   = blockIdx.x * 2 + (tid >> 6);
    const int token = tokens[b * S + t];
    const float* xrow = emb + (size_t)token * H;
    const float* hrow = h_prev + b * H;
    float acc[4];
    #pragma unroll
    for (int g = 0; g < 4; ++g) acc[g] = b_ih[g * H + k] + b_hh[g * H + k];
    for (int d = 0; d < H; ++d) {
        const float xv = xrow[d], hv = hrow[d];
        #pragma unroll
        for (int g = 0; g < 4; ++g)
            acc[g] += xv * W_ih[(size_t)(g * H + k) * H + d] + hv * W_hh[(size_t)(g * H + k) * H + d];
    }
    const float ig = sigmoidf_(acc[0]);
    const float fg = sigmoidf_(acc[1]);
    const float gg = tanhf(acc[2]);
    const float og = sigmoidf_(acc[3]);
    const int ck = b * H + k;
    const float cn = fg * c_st[ck] + ig * gg;
    c_st[ck] = cn;
    const float hn = og * tanhf(cn);
    h_next[ck] = hn;
    out[(size_t)b * S * H + (size_t)t * H + k] = hn;
    if (t == S - 1) {
        out[(size_t)B * S * H + ck] = hn;
        out[(size_t)B * S * H + B * H + ck] = cn;
    }
}

extern "C" void kernel_launch(void* const* d_in, const int* in_sizes, int n_in,
                              void* d_out, int out_size, void* d_ws, size_t ws_size,
                              hipStream_t stream)
{
    const int*   tokens = (const int*)d_in[0];
    const float* emb    = (const float*)d_in[1];
    const float* W_ih   = (const float*)d_in[2];
    const float* W_hh   = (const float*)d_in[3];
    const float* b_ih   = (const float*)d_in[4];
    const float* b_hh   = (const float*)d_in[5];
    float* out = (float*)d_out;

    // ws layout: xg bf16 [S][G4][B] | hist f32 [S+1][H][B] | c f32 [H][B]
    const size_t XG_BYTES   = (size_t)S * G4 * B * 2;        // 134217728
    const size_t HIST_BYTES = (size_t)(S + 1) * H * B * 4;   // 67239936
    const size_t C_BYTES    = (size_t)H * B * 4;             // 131072
    const size_t NEED = XG_BYTES + HIST_BYTES + C_BYTES;

    if (ws_size >= NEED) {
        ushort* xg   = (ushort*)d_ws;
        float*  hist = (float*)((char*)d_ws + XG_BYTES);
        float*  c_st = (float*)((char*)d_ws + XG_BYTES + HIST_BYTES);

        (void)hipMemsetAsync(hist, 0, (size_t)H * B * 4, stream);   // h_0 = 0
        (void)hipMemsetAsync(c_st, 0, C_BYTES, stream);             // c_0 = 0

        xg_gemm<<<dim3(S, 16), dim3(256), 0, stream>>>(tokens, emb, W_ih, b_ih, b_hh, xg);

        for (int t = 0; t < S; ++t)
            lstm_step<<<dim3(H), dim3(256), 0, stream>>>(W_hh, xg, hist, c_st, t);

        finalize<<<dim3(S + 1, 8), dim3(256), 0, stream>>>(hist, c_st, out);
    } else {
        // fallback: round-2 correct path (needs 3*B*H floats)
        float* c_st = (float*)d_ws;
        float* h0   = c_st + B * H;
        float* h1   = h0 + B * H;
        (void)hipMemsetAsync(d_ws, 0, (size_t)3 * B * H * sizeof(float), stream);
        for (int t = 0; t < S; ++t) {
            const float* hp = (t & 1) ? h1 : h0;
            float*       hn = (t & 1) ? h0 : h1;
            lstm_step_fb<<<dim3(256), dim3(128), 0, stream>>>(
                tokens, emb, W_ih, W_hh, b_ih, b_hh, hp, hn, c_st, out, t);
        }
    }
}